// Round 2
// baseline (996.757 us; speedup 1.0000x reference)
//
#include <hip/hip_runtime.h>

#define NN 100000
#define NE 1600000
#define NT (NE / 16)          // 100000 wave-tiles, 16 edges each

typedef short v8s __attribute__((ext_vector_type(8)));
typedef float v4f __attribute__((ext_vector_type(4)));
typedef unsigned short v4u16 __attribute__((ext_vector_type(4)));

__device__ __forceinline__ unsigned short f2bf(float f) {
    union { float f; unsigned int u; } v; v.f = f;
    unsigned int r = v.u + 0x7FFFu + ((v.u >> 16) & 1u);  // RNE
    return (unsigned short)(r >> 16);
}
__device__ __forceinline__ float bf2f(unsigned short u) {
    union { unsigned int i; float f; } v; v.i = ((unsigned int)u) << 16;
    return v.f;
}

__device__ __forceinline__ v8s pack8(float4 a, float4 b) {
    union { v8s v; unsigned short u[8]; } t;
    t.u[0] = f2bf(a.x); t.u[1] = f2bf(a.y); t.u[2] = f2bf(a.z); t.u[3] = f2bf(a.w);
    t.u[4] = f2bf(b.x); t.u[5] = f2bf(b.y); t.u[6] = f2bf(b.z); t.u[7] = f2bf(b.w);
    return t.v;
}

// Swizzled fragment layout within one 32-k block: element (row, k) at
//   row*32 + ((((k>>3)&3) ^ ((row>>1)&3)) << 3) + (k&7)
__device__ __forceinline__ int wfrag(int row, int k) {   // k in 0..31
    return row * 32 + ((((k >> 3) & 3) ^ ((row >> 1) & 3)) << 3) + (k & 7);
}
__device__ __forceinline__ int hoff(int m, int k) {      // k in 0..63, 16-row blocks
    return (k >> 5) * 512 + m * 32 + ((((k >> 3) & 3) ^ ((m >> 1) & 3)) << 3) + (k & 7);
}

// Node kernel (both variants) uses the unswizzled 64-row layout helper.
__device__ __forceinline__ void store_bf4(unsigned short* base, int row, int k, float4 v) {
    v4u16 p;
    p.x = f2bf(v.x); p.y = f2bf(v.y); p.z = f2bf(v.z); p.w = f2bf(v.w);
    *(v4u16*)(base + ((k >> 5) * 2048 + row * 32 + (k & 31))) = p;
}

#define MFMA16(acc, a, b) acc = __builtin_amdgcn_mfma_f32_16x16x32_bf16(a, b, acc, 0, 0, 0)

// ===========================================================================
// CSR build: histogram + single-block scan.
// cursor[] holds counts on entry to scan; on exit cursor==rowptr[0..NN).
// ===========================================================================
__global__ void hist_kernel(const int* __restrict__ rcv, int* __restrict__ cursor) {
    int i = blockIdx.x * blockDim.x + threadIdx.x;
    int stride = gridDim.x * blockDim.x;
    for (; i < NE; i += stride) atomicAdd(&cursor[rcv[i]], 1);
}

__global__ __launch_bounds__(1024) void scan_kernel(int* __restrict__ cursor,
                                                    int* __restrict__ rowptr) {
    __shared__ int wsum[16];
    __shared__ int chunk_total;
    const int tid = threadIdx.x;
    const int lane = tid & 63, wv = tid >> 6;
    int running = 0;
    for (int base = 0; base < NN; base += 1024) {
        int i = base + tid;
        int v = (i < NN) ? cursor[i] : 0;
        // wave-inclusive scan (shfl, no barriers)
        int s = v;
#pragma unroll
        for (int d = 1; d < 64; d <<= 1) {
            int t = __shfl_up(s, d);
            if (lane >= d) s += t;
        }
        if (lane == 63) wsum[wv] = s;
        __syncthreads();
        if (wv == 0 && lane < 16) {
            int ws = wsum[lane];
            int ss = ws;
#pragma unroll
            for (int d = 1; d < 16; d <<= 1) {
                int t = __shfl_up(ss, d, 16);
                if (lane >= d) ss += t;
            }
            wsum[lane] = ss - ws;   // exclusive prefix of wave sums
        }
        __syncthreads();
        int excl = running + wsum[wv] + (s - v);
        if (i < NN) { rowptr[i] = excl; cursor[i] = excl; }
        if (tid == 1023) chunk_total = wsum[15] + s;
        __syncthreads();
        running += chunk_total;
        __syncthreads();   // wsum/chunk_total reused next chunk
    }
    if (tid == 0) rowptr[NN] = running;   // == NE
}

// ===========================================================================
// Edge kernel, CSR variant: per-wave 16-edge tile, barrier-free main loop.
// Layer-3 rows are written (bf16) into e_new at slots grabbed from cursor[rcv]
// -> rows of each receiver are contiguous; NO f32 atomics.
// ===========================================================================
__global__ __launch_bounds__(512, 4) void edge_kernel_csr(
    const float* __restrict__ x, const float* __restrict__ e,
    const int* __restrict__ snd, const int* __restrict__ rcv,
    const float* __restrict__ We1, const float* __restrict__ be1,
    const float* __restrict__ We2, const float* __restrict__ be2,
    const float* __restrict__ We3, const float* __restrict__ be3,
    unsigned short* __restrict__ enew, int* __restrict__ cursor)
{
    extern __shared__ unsigned short smem[];
    unsigned short* WT1 = smem;             // 12288 u16 (6 kb blocks of 64x32)
    unsigned short* WT2 = WT1 + 12288;      // 4096
    unsigned short* WT3 = WT2 + 4096;       // 4096
    unsigned short* HS  = WT3 + 4096;       // 8 * 1024 per-wave scratch

    const int tid = threadIdx.x;

    for (int idx = tid; idx < 192 * 64; idx += 512) {
        int k = idx >> 6, n = idx & 63;
        WT1[(k >> 5) * 2048 + wfrag(n, k & 31)] = f2bf(We1[idx]);
    }
    for (int idx = tid; idx < 64 * 64; idx += 512) {
        int k = idx >> 6, n = idx & 63;
        int off = (k >> 5) * 2048 + wfrag(n, k & 31);
        WT2[off] = f2bf(We2[idx]);
        WT3[off] = f2bf(We3[idx]);
    }

    const int lane = tid & 63;
    const int wv   = tid >> 6;
    const int l15  = lane & 15;
    const int quad = lane >> 4;
    unsigned short* H = HS + wv * 1024;     // 16 rows x 64 k, swizzled

    float b1v[4], b2v[4], b3v[4];
#pragma unroll
    for (int nt = 0; nt < 4; ++nt) {
        b1v[nt] = be1[nt * 16 + l15];
        b2v[nt] = be2[nt * 16 + l15];
        b3v[nt] = be3[nt * 16 + l15];
    }

    const int swz = l15 * 32 + ((quad ^ ((l15 >> 1) & 3)) << 3);

    __syncthreads();   // weights ready; the ONLY block barrier.

    const int nwaves = gridDim.x * (blockDim.x >> 6);
    int wt = blockIdx.x * (blockDim.x >> 6) + wv;

    int er = wt * 16 + l15;
    int s0 = snd[er], r0 = rcv[er];

    const int crow = lane >> 2, cchk = lane & 3;   // copy-out role: row, 16B chunk

    while (wt < NT) {
        const int ebase = wt * 16;
        const int s = s0, rcur = r0;

        const float* erow = e + (size_t)(ebase + l15) * 64 + quad * 8;
        const float* xs   = x + (size_t)s    * 64 + quad * 8;
        const float* xr   = x + (size_t)rcur * 64 + quad * 8;

        float4 e00 = *(const float4*)(erow);
        float4 e01 = *(const float4*)(erow + 4);
        float4 e10 = *(const float4*)(erow + 32);
        float4 e11 = *(const float4*)(erow + 36);
        float4 s00 = *(const float4*)(xs);
        float4 s01 = *(const float4*)(xs + 4);
        float4 s10 = *(const float4*)(xs + 32);
        float4 s11 = *(const float4*)(xs + 36);
        float4 r00 = *(const float4*)(xr);
        float4 r01 = *(const float4*)(xr + 4);
        float4 r10 = *(const float4*)(xr + 32);
        float4 r11 = *(const float4*)(xr + 36);

        const int wtn = wt + nwaves;
        if (wtn < NT) {
            int ern = wtn * 16 + l15;
            s0 = snd[ern];
            r0 = rcv[ern];
        }

        v8s af[6];
        af[0] = pack8(e00, e01); af[1] = pack8(e10, e11);
        af[2] = pack8(s00, s01); af[3] = pack8(s10, s11);
        af[4] = pack8(r00, r01); af[5] = pack8(r10, r11);

        // ---- Layer 1: [16,192] @ [192,64], relu -> H ----
        {
            v4f acc[4];
#pragma unroll
            for (int nt = 0; nt < 4; ++nt) acc[nt] = (v4f){0.f, 0.f, 0.f, 0.f};
#pragma unroll
            for (int kb = 0; kb < 6; ++kb) {
#pragma unroll
                for (int nt = 0; nt < 4; ++nt) {
                    v8s bf = *(const v8s*)(WT1 + kb * 2048 + nt * 512 + swz);
                    MFMA16(acc[nt], af[kb], bf);
                }
            }
#pragma unroll
            for (int nt = 0; nt < 4; ++nt) {
                int kk = nt * 16 + l15;
#pragma unroll
                for (int r = 0; r < 4; ++r) {
                    float v = acc[nt][r] + b1v[nt];
                    v = v > 0.f ? v : 0.f;
                    H[hoff(quad * 4 + r, kk)] = f2bf(v);
                }
            }
        }

        // ---- Layer 2: [16,64] @ [64,64], relu -> H (in-place) ----
        {
            v8s a0 = *(const v8s*)(H + swz);
            v8s a1 = *(const v8s*)(H + 512 + swz);
            v4f acc[4];
#pragma unroll
            for (int nt = 0; nt < 4; ++nt) acc[nt] = (v4f){0.f, 0.f, 0.f, 0.f};
#pragma unroll
            for (int nt = 0; nt < 4; ++nt) {
                v8s bf0 = *(const v8s*)(WT2 + nt * 512 + swz);
                MFMA16(acc[nt], a0, bf0);
                v8s bf1 = *(const v8s*)(WT2 + 2048 + nt * 512 + swz);
                MFMA16(acc[nt], a1, bf1);
            }
#pragma unroll
            for (int nt = 0; nt < 4; ++nt) {
                int kk = nt * 16 + l15;
#pragma unroll
                for (int r = 0; r < 4; ++r) {
                    float v = acc[nt][r] + b2v[nt];
                    v = v > 0.f ? v : 0.f;
                    H[hoff(quad * 4 + r, kk)] = f2bf(v);
                }
            }
        }

        // ---- Layer 3: [16,64] @ [64,64] (no relu) -> e_new row store ----
        {
            v8s a0 = *(const v8s*)(H + swz);
            v8s a1 = *(const v8s*)(H + 512 + swz);
            v4f acc[4];
#pragma unroll
            for (int nt = 0; nt < 4; ++nt) acc[nt] = (v4f){0.f, 0.f, 0.f, 0.f};
#pragma unroll
            for (int nt = 0; nt < 4; ++nt) {
                v8s bf0 = *(const v8s*)(WT3 + nt * 512 + swz);
                MFMA16(acc[nt], a0, bf0);
                v8s bf1 = *(const v8s*)(WT3 + 2048 + nt * 512 + swz);
                MFMA16(acc[nt], a1, bf1);
            }
            // bf16 rows back into H (swizzled, same as layer 2 store, no relu)
#pragma unroll
            for (int nt = 0; nt < 4; ++nt) {
                int kk = nt * 16 + l15;
#pragma unroll
                for (int r = 0; r < 4; ++r) {
                    H[hoff(quad * 4 + r, kk)] = f2bf(acc[nt][r] + b3v[nt]);
                }
            }
            // grab one CSR slot per edge (lanes 0..15), broadcast, copy out.
            int pos = 0;
            if (quad == 0) pos = atomicAdd(cursor + rcur, 1);
            int posr = __shfl(pos, crow);           // slot for row crow
            unsigned short* dst = enew + (size_t)posr * 64 + cchk * 8;
#pragma unroll
            for (int kb = 0; kb < 2; ++kb) {
                v8s d = *(const v8s*)(H + kb * 512 + crow * 32 +
                                      ((cchk ^ ((crow >> 1) & 3)) << 3));
                *(v8s*)(dst + kb * 32) = d;
            }
        }

        wt = wtn;
    }
}

// ===========================================================================
// Node kernel, CSR variant: per-wave aggregation of contiguous e_new runs
// into the A tile (agg half), then the fused 3-layer MFMA MLP.
// ===========================================================================
__global__ __launch_bounds__(256, 2) void node_kernel_csr(
    const float* __restrict__ x,
    const unsigned short* __restrict__ enew, const int* __restrict__ rowptr,
    const float* __restrict__ Wn1, const float* __restrict__ bn1,
    const float* __restrict__ Wn2, const float* __restrict__ bn2,
    const float* __restrict__ Wn3, const float* __restrict__ bn3,
    float* __restrict__ out)
{
    extern __shared__ unsigned short smem[];
    unsigned short* WT1 = smem;             // 8192 (kb 0..3)
    unsigned short* WT2 = WT1 + 8192;       // 4096
    unsigned short* WT3 = WT2 + 4096;       // 4096
    unsigned short* A   = WT3 + 4096;       // 8192 (kb 0..3)

    const int tid = threadIdx.x;

    for (int idx = tid; idx < 128 * 64; idx += 256) {
        int k = idx >> 6, n = idx & 63;
        WT1[(k >> 5) * 2048 + n * 32 + (k & 31)] = f2bf(Wn1[idx]);
    }
    for (int idx = tid; idx < 64 * 64; idx += 256) {
        int k = idx >> 6, n = idx & 63;
        int off = (k >> 5) * 2048 + n * 32 + (k & 31);
        WT2[off] = f2bf(Wn2[idx]);
        WT3[off] = f2bf(Wn3[idx]);
    }

    const int lane = tid & 63;
    const int wv   = tid >> 6;
    const int l15  = lane & 15;
    const int quad = lane >> 4;
    const int astrip = wv * 16;
    const int nbase = blockIdx.x * 64;

    float b1v[4], b2v[4], b3v[4];
#pragma unroll
    for (int nt = 0; nt < 4; ++nt) {
        b1v[nt] = bn1[nt * 16 + l15];
        b2v[nt] = bn2[nt * 16 + l15];
        b3v[nt] = bn3[nt * 16 + l15];
    }

    // ---- x half of A (k 0..63), block-cooperative coalesced load ----
#pragma unroll
    for (int t = 0; t < 2; ++t) {
        int idx = tid + t * 256;        // 0..511
        int row = idx >> 3;             // 0..63
        int k0  = (idx & 7) * 8;        // 0..56
        int node = nbase + row;
        float4 v0 = {0.f, 0.f, 0.f, 0.f}, v1 = {0.f, 0.f, 0.f, 0.f};
        if (node < NN) {
            v0 = *(const float4*)(x + (size_t)node * 64 + k0);
            v1 = *(const float4*)(x + (size_t)node * 64 + k0 + 4);
        }
        store_bf4(A, row, k0, v0);
        store_bf4(A, row, k0 + 4, v1);
    }

    // ---- agg half of A (k 64..127): wave wv aggregates nodes [astrip, astrip+16) ----
    const int rsub = lane >> 3;    // 0..7: row-within-8-row-chunk
    const int csub = lane & 7;     // 0..7: 8-col chunk
    for (int j = 0; j < 16; ++j) {
        int node = nbase + astrip + j;
        float av[8] = {0.f, 0.f, 0.f, 0.f, 0.f, 0.f, 0.f, 0.f};
        if (node < NN) {
            int start = rowptr[node], end = rowptr[node + 1];
            for (int r0 = start; r0 < end; r0 += 8) {
                int rr = r0 + rsub;
                if (rr < end) {
                    v8s d = *(const v8s*)(enew + (size_t)rr * 64 + csub * 8);
#pragma unroll
                    for (int k = 0; k < 8; ++k) av[k] += bf2f((unsigned short)d[k]);
                }
            }
        }
        // reduce the 8 row-groups (lane bits 3..5)
#pragma unroll
        for (int m = 8; m < 64; m <<= 1) {
#pragma unroll
            for (int k = 0; k < 8; ++k) av[k] += __shfl_xor(av[k], m);
        }
        if (rsub == 0) {
            float4 a = {av[0], av[1], av[2], av[3]};
            float4 b = {av[4], av[5], av[6], av[7]};
            store_bf4(A, astrip + j, 64 + csub * 8, a);
            store_bf4(A, astrip + j, 64 + csub * 8 + 4, b);
        }
    }

    const int arow = (astrip + l15) * 32 + quad * 8;
    const int brow = l15 * 32 + quad * 8;

    __syncthreads();

    // ---- Layer 1: K=128, relu -> A kb0-1 ----
    {
        v4f acc[4];
#pragma unroll
        for (int nt = 0; nt < 4; ++nt) acc[nt] = (v4f){0.f, 0.f, 0.f, 0.f};
#pragma unroll
        for (int kb = 0; kb < 4; ++kb) {
            v8s af = *(const v8s*)(A + kb * 2048 + arow);
#pragma unroll
            for (int nt = 0; nt < 4; ++nt) {
                v8s bf = *(const v8s*)(WT1 + kb * 2048 + brow + nt * 512);
                MFMA16(acc[nt], af, bf);
            }
        }
#pragma unroll
        for (int nt = 0; nt < 4; ++nt) {
            int kk = nt * 16 + l15;
#pragma unroll
            for (int r = 0; r < 4; ++r) {
                int m = astrip + quad * 4 + r;
                float v = acc[nt][r] + b1v[nt];
                v = v > 0.f ? v : 0.f;
                A[(kk >> 5) * 2048 + m * 32 + (kk & 31)] = f2bf(v);
            }
        }
    }

    // ---- Layer 2: K=64, relu -> A kb2-3 ----
    {
        v4f acc[4];
#pragma unroll
        for (int nt = 0; nt < 4; ++nt) acc[nt] = (v4f){0.f, 0.f, 0.f, 0.f};
#pragma unroll
        for (int kb = 0; kb < 2; ++kb) {
            v8s af = *(const v8s*)(A + kb * 2048 + arow);
#pragma unroll
            for (int nt = 0; nt < 4; ++nt) {
                v8s bf = *(const v8s*)(WT2 + kb * 2048 + brow + nt * 512);
                MFMA16(acc[nt], af, bf);
            }
        }
#pragma unroll
        for (int nt = 0; nt < 4; ++nt) {
            int kk = nt * 16 + l15;
#pragma unroll
            for (int r = 0; r < 4; ++r) {
                int m = astrip + quad * 4 + r;
                float v = acc[nt][r] + b2v[nt];
                v = v > 0.f ? v : 0.f;
                A[(2 + (kk >> 5)) * 2048 + m * 32 + (kk & 31)] = f2bf(v);
            }
        }
    }

    // ---- Layer 3: K=64, no relu -> out ----
    {
        v4f acc[4];
#pragma unroll
        for (int nt = 0; nt < 4; ++nt) acc[nt] = (v4f){0.f, 0.f, 0.f, 0.f};
#pragma unroll
        for (int kb = 0; kb < 2; ++kb) {
            v8s af = *(const v8s*)(A + (2 + kb) * 2048 + arow);
#pragma unroll
            for (int nt = 0; nt < 4; ++nt) {
                v8s bf = *(const v8s*)(WT3 + kb * 2048 + brow + nt * 512);
                MFMA16(acc[nt], af, bf);
            }
        }
#pragma unroll
        for (int r = 0; r < 4; ++r) {
            int node = nbase + astrip + quad * 4 + r;
            if (node < NN) {
#pragma unroll
                for (int nt = 0; nt < 4; ++nt) {
                    out[(size_t)node * 64 + nt * 16 + l15] = acc[nt][r] + b3v[nt];
                }
            }
        }
    }
}

// ===========================================================================
// FALLBACK path (round-1 kernels, atomic aggregation) — used when the
// workspace is too small for the CSR e_new buffer.
// ===========================================================================
__global__ __launch_bounds__(512, 4) void edge_kernel_atomic(
    const float* __restrict__ x, const float* __restrict__ e,
    const int* __restrict__ snd, const int* __restrict__ rcv,
    const float* __restrict__ We1, const float* __restrict__ be1,
    const float* __restrict__ We2, const float* __restrict__ be2,
    const float* __restrict__ We3, const float* __restrict__ be3,
    float* agg)
{
    extern __shared__ unsigned short smem[];
    unsigned short* WT1 = smem;
    unsigned short* WT2 = WT1 + 12288;
    unsigned short* WT3 = WT2 + 4096;
    unsigned short* HS  = WT3 + 4096;

    const int tid = threadIdx.x;

    for (int idx = tid; idx < 192 * 64; idx += 512) {
        int k = idx >> 6, n = idx & 63;
        WT1[(k >> 5) * 2048 + wfrag(n, k & 31)] = f2bf(We1[idx]);
    }
    for (int idx = tid; idx < 64 * 64; idx += 512) {
        int k = idx >> 6, n = idx & 63;
        int off = (k >> 5) * 2048 + wfrag(n, k & 31);
        WT2[off] = f2bf(We2[idx]);
        WT3[off] = f2bf(We3[idx]);
    }

    const int lane = tid & 63;
    const int wv   = tid >> 6;
    const int l15  = lane & 15;
    const int quad = lane >> 4;
    unsigned short* H = HS + wv * 1024;

    float b1v[4], b2v[4], b3v[4];
#pragma unroll
    for (int nt = 0; nt < 4; ++nt) {
        b1v[nt] = be1[nt * 16 + l15];
        b2v[nt] = be2[nt * 16 + l15];
        b3v[nt] = be3[nt * 16 + l15];
    }

    const int swz = l15 * 32 + ((quad ^ ((l15 >> 1) & 3)) << 3);

    __syncthreads();

    const int nwaves = gridDim.x * (blockDim.x >> 6);
    int wt = blockIdx.x * (blockDim.x >> 6) + wv;

    int er = wt * 16 + l15;
    int s0 = snd[er], r0 = rcv[er];

    while (wt < NT) {
        const int ebase = wt * 16;
        const int s = s0, rcur = r0;

        const float* erow = e + (size_t)(ebase + l15) * 64 + quad * 8;
        const float* xs   = x + (size_t)s    * 64 + quad * 8;
        const float* xr   = x + (size_t)rcur * 64 + quad * 8;

        float4 e00 = *(const float4*)(erow);
        float4 e01 = *(const float4*)(erow + 4);
        float4 e10 = *(const float4*)(erow + 32);
        float4 e11 = *(const float4*)(erow + 36);
        float4 s00 = *(const float4*)(xs);
        float4 s01 = *(const float4*)(xs + 4);
        float4 s10 = *(const float4*)(xs + 32);
        float4 s11 = *(const float4*)(xs + 36);
        float4 r00 = *(const float4*)(xr);
        float4 r01 = *(const float4*)(xr + 4);
        float4 r10 = *(const float4*)(xr + 32);
        float4 r11 = *(const float4*)(xr + 36);

        const int wtn = wt + nwaves;
        if (wtn < NT) {
            int ern = wtn * 16 + l15;
            s0 = snd[ern];
            r0 = rcv[ern];
        }

        v8s af[6];
        af[0] = pack8(e00, e01); af[1] = pack8(e10, e11);
        af[2] = pack8(s00, s01); af[3] = pack8(s10, s11);
        af[4] = pack8(r00, r01); af[5] = pack8(r10, r11);

        {
            v4f acc[4];
#pragma unroll
            for (int nt = 0; nt < 4; ++nt) acc[nt] = (v4f){0.f, 0.f, 0.f, 0.f};
#pragma unroll
            for (int kb = 0; kb < 6; ++kb) {
#pragma unroll
                for (int nt = 0; nt < 4; ++nt) {
                    v8s bf = *(const v8s*)(WT1 + kb * 2048 + nt * 512 + swz);
                    MFMA16(acc[nt], af[kb], bf);
                }
            }
#pragma unroll
            for (int nt = 0; nt < 4; ++nt) {
                int kk = nt * 16 + l15;
#pragma unroll
                for (int r = 0; r < 4; ++r) {
                    float v = acc[nt][r] + b1v[nt];
                    v = v > 0.f ? v : 0.f;
                    H[hoff(quad * 4 + r, kk)] = f2bf(v);
                }
            }
        }

        {
            v8s a0 = *(const v8s*)(H + swz);
            v8s a1 = *(const v8s*)(H + 512 + swz);
            v4f acc[4];
#pragma unroll
            for (int nt = 0; nt < 4; ++nt) acc[nt] = (v4f){0.f, 0.f, 0.f, 0.f};
#pragma unroll
            for (int nt = 0; nt < 4; ++nt) {
                v8s bf0 = *(const v8s*)(WT2 + nt * 512 + swz);
                MFMA16(acc[nt], a0, bf0);
                v8s bf1 = *(const v8s*)(WT2 + 2048 + nt * 512 + swz);
                MFMA16(acc[nt], a1, bf1);
            }
#pragma unroll
            for (int nt = 0; nt < 4; ++nt) {
                int kk = nt * 16 + l15;
#pragma unroll
                for (int r = 0; r < 4; ++r) {
                    float v = acc[nt][r] + b2v[nt];
                    v = v > 0.f ? v : 0.f;
                    H[hoff(quad * 4 + r, kk)] = f2bf(v);
                }
            }
        }

        {
            v8s a0 = *(const v8s*)(H + swz);
            v8s a1 = *(const v8s*)(H + 512 + swz);
            v4f acc[4];
#pragma unroll
            for (int nt = 0; nt < 4; ++nt) acc[nt] = (v4f){0.f, 0.f, 0.f, 0.f};
#pragma unroll
            for (int nt = 0; nt < 4; ++nt) {
                v8s bf0 = *(const v8s*)(WT3 + nt * 512 + swz);
                MFMA16(acc[nt], a0, bf0);
                v8s bf1 = *(const v8s*)(WT3 + 2048 + nt * 512 + swz);
                MFMA16(acc[nt], a1, bf1);
            }
#pragma unroll
            for (int ri = 0; ri < 4; ++ri) {
                int dst = __shfl(rcur, quad * 4 + ri, 16);
                float* aggrow = agg + (size_t)dst * 64;
#pragma unroll
                for (int nt = 0; nt < 4; ++nt) {
                    unsafeAtomicAdd(aggrow + nt * 16 + l15, acc[nt][ri] + b3v[nt]);
                }
            }
        }

        wt = wtn;
    }
}

__global__ __launch_bounds__(256, 2) void node_kernel_atomic(
    const float* __restrict__ x,
    const float* __restrict__ Wn1, const float* __restrict__ bn1,
    const float* __restrict__ Wn2, const float* __restrict__ bn2,
    const float* __restrict__ Wn3, const float* __restrict__ bn3,
    float* aggout)
{
    extern __shared__ unsigned short smem[];
    unsigned short* WT1 = smem;
    unsigned short* WT2 = WT1 + 8192;
    unsigned short* WT3 = WT2 + 4096;
    unsigned short* A   = WT3 + 4096;

    const int tid = threadIdx.x;

    for (int idx = tid; idx < 128 * 64; idx += 256) {
        int k = idx >> 6, n = idx & 63;
        WT1[(k >> 5) * 2048 + n * 32 + (k & 31)] = f2bf(Wn1[idx]);
    }
    for (int idx = tid; idx < 64 * 64; idx += 256) {
        int k = idx >> 6, n = idx & 63;
        int off = (k >> 5) * 2048 + n * 32 + (k & 31);
        WT2[off] = f2bf(Wn2[idx]);
        WT3[off] = f2bf(Wn3[idx]);
    }

    const int lane = tid & 63;
    const int wv   = tid >> 6;
    const int l15  = lane & 15;
    const int quad = lane >> 4;
    const int astrip = wv * 16;

    float b1v[4], b2v[4], b3v[4];
#pragma unroll
    for (int nt = 0; nt < 4; ++nt) {
        b1v[nt] = bn1[nt * 16 + l15];
        b2v[nt] = bn2[nt * 16 + l15];
        b3v[nt] = bn3[nt * 16 + l15];
    }

    const int arow = (astrip + l15) * 32 + quad * 8;
    const int brow = l15 * 32 + quad * 8;
    const int nbase = blockIdx.x * 64;

    __syncthreads();

#pragma unroll
    for (int t = 0; t < 4; ++t) {
        int idx = tid + t * 256;
        int row = idx >> 4;
        int k0  = (idx & 15) * 4;
        int node = nbase + row;
        float4 vx = {0.f, 0.f, 0.f, 0.f}, va = {0.f, 0.f, 0.f, 0.f};
        if (node < NN) {
            vx = *(const float4*)(x + (size_t)node * 64 + k0);
            va = *(const float4*)(aggout + (size_t)node * 64 + k0);
        }
        store_bf4(A, row, k0, vx);
        store_bf4(A, row, 64 + k0, va);
    }
    __syncthreads();

    {
        v4f acc[4];
#pragma unroll
        for (int nt = 0; nt < 4; ++nt) acc[nt] = (v4f){0.f, 0.f, 0.f, 0.f};
#pragma unroll
        for (int kb = 0; kb < 4; ++kb) {
            v8s af = *(const v8s*)(A + kb * 2048 + arow);
#pragma unroll
            for (int nt = 0; nt < 4; ++nt) {
                v8s bf = *(const v8s*)(WT1 + kb * 2048 + brow + nt * 512);
                MFMA16(acc[nt], af, bf);
            }
        }
#pragma unroll
        for (int nt = 0; nt < 4; ++nt) {
            int kk = nt * 16 + l15;
#pragma unroll
            for (int r = 0; r < 4; ++r) {
                int m = astrip + quad * 4 + r;
                float v = acc[nt][r] + b1v[nt];
                v = v > 0.f ? v : 0.f;
                A[(kk >> 5) * 2048 + m * 32 + (kk & 31)] = f2bf(v);
            }
        }
    }

    {
        v4f acc[4];
#pragma unroll
        for (int nt = 0; nt < 4; ++nt) acc[nt] = (v4f){0.f, 0.f, 0.f, 0.f};
#pragma unroll
        for (int kb = 0; kb < 2; ++kb) {
            v8s af = *(const v8s*)(A + kb * 2048 + arow);
#pragma unroll
            for (int nt = 0; nt < 4; ++nt) {
                v8s bf = *(const v8s*)(WT2 + kb * 2048 + brow + nt * 512);
                MFMA16(acc[nt], af, bf);
            }
        }
#pragma unroll
        for (int nt = 0; nt < 4; ++nt) {
            int kk = nt * 16 + l15;
#pragma unroll
            for (int r = 0; r < 4; ++r) {
                int m = astrip + quad * 4 + r;
                float v = acc[nt][r] + b2v[nt];
                v = v > 0.f ? v : 0.f;
                A[(2 + (kk >> 5)) * 2048 + m * 32 + (kk & 31)] = f2bf(v);
            }
        }
    }

    {
        v4f acc[4];
#pragma unroll
        for (int nt = 0; nt < 4; ++nt) acc[nt] = (v4f){0.f, 0.f, 0.f, 0.f};
#pragma unroll
        for (int kb = 0; kb < 2; ++kb) {
            v8s af = *(const v8s*)(A + (2 + kb) * 2048 + arow);
#pragma unroll
            for (int nt = 0; nt < 4; ++nt) {
                v8s bf = *(const v8s*)(WT3 + kb * 2048 + brow + nt * 512);
                MFMA16(acc[nt], af, bf);
            }
        }
#pragma unroll
        for (int r = 0; r < 4; ++r) {
            int node = nbase + astrip + quad * 4 + r;
            if (node < NN) {
#pragma unroll
                for (int nt = 0; nt < 4; ++nt) {
                    aggout[(size_t)node * 64 + nt * 16 + l15] = acc[nt][r] + b3v[nt];
                }
            }
        }
    }
}

extern "C" void kernel_launch(void* const* d_in, const int* in_sizes, int n_in,
                              void* d_out, int out_size, void* d_ws, size_t ws_size,
                              hipStream_t stream) {
    const float* x   = (const float*)d_in[0];
    const float* e   = (const float*)d_in[1];
    const int*   snd = (const int*)d_in[2];
    const int*   rcv = (const int*)d_in[3];
    const float* We1 = (const float*)d_in[4];  const float* be1 = (const float*)d_in[5];
    const float* We2 = (const float*)d_in[6];  const float* be2 = (const float*)d_in[7];
    const float* We3 = (const float*)d_in[8];  const float* be3 = (const float*)d_in[9];
    const float* Wn1 = (const float*)d_in[10]; const float* bn1 = (const float*)d_in[11];
    const float* Wn2 = (const float*)d_in[12]; const float* bn2 = (const float*)d_in[13];
    const float* Wn3 = (const float*)d_in[14]; const float* bn3 = (const float*)d_in[15];
    float* out = (float*)d_out;

    const size_t ENEW_BYTES = (size_t)NE * 64 * 2;          // 204,800,000 (bf16 rows)
    const size_t ROWPTR_OFF = ENEW_BYTES;                   // (NN+1)*4, padded
    const size_t CURSOR_OFF = ROWPTR_OFF + 400016;
    const size_t WS_REQ     = CURSOR_OFF + (size_t)NN * 4;  // ~205.6 MB

    if (d_ws != nullptr && ws_size >= WS_REQ) {
        // ---- CSR two-phase path: no f32 atomics ----
        unsigned short* enew = (unsigned short*)d_ws;
        int* rowptr = (int*)((char*)d_ws + ROWPTR_OFF);
        int* cursor = (int*)((char*)d_ws + CURSOR_OFF);

        hipMemsetAsync(cursor, 0, (size_t)NN * 4, stream);
        hist_kernel<<<1024, 256, 0, stream>>>(rcv, cursor);
        scan_kernel<<<1, 1024, 0, stream>>>(cursor, rowptr);
        edge_kernel_csr<<<512, 512, 57344, stream>>>(x, e, snd, rcv,
                                                     We1, be1, We2, be2, We3, be3,
                                                     enew, cursor);
        node_kernel_csr<<<(NN + 63) / 64, 256, 49152, stream>>>(x, enew, rowptr,
                                                                Wn1, bn1, Wn2, bn2, Wn3, bn3,
                                                                out);
    } else {
        // ---- fallback: round-1 atomic path ----
        hipMemsetAsync(out, 0, (size_t)NN * 64 * sizeof(float), stream);
        edge_kernel_atomic<<<512, 512, 57344, stream>>>(x, e, snd, rcv,
                                                        We1, be1, We2, be2, We3, be3,
                                                        out);
        node_kernel_atomic<<<(NN + 63) / 64, 256, 49152, stream>>>(x,
                                                                   Wn1, bn1, Wn2, bn2, Wn3, bn3,
                                                                   out);
    }
}